// Round 5
// baseline (182.227 us; speedup 1.0000x reference)
//
#include <hip/hip_runtime.h>
#include <math.h>

typedef __attribute__((ext_vector_type(8)))  short short8;
typedef __attribute__((ext_vector_type(16))) float float16_t;

__device__ __forceinline__ short f2bf(float f) {          // RNE (prep only)
    union { float f; unsigned u; } c; c.f = f;
    unsigned u = c.u + 0x7fffu + ((c.u >> 16) & 1u);
    return (short)(u >> 16);
}
__device__ __forceinline__ unsigned fbits(float f) {
    union { float f; unsigned u; } c; c.f = f; return c.u;
}
__device__ __forceinline__ float16_t zero16() {
    float16_t z;
#pragma unroll
    for (int r = 0; r < 16; ++r) z[r] = 0.0f;
    return z;
}

// ---------------------------------------------------------------------------
// Prep (fp32 in -> bf16 out):
//   Qz  = cos(x[...,:8])*cos(theta)            -> bf16 [32768][8]
//   W1z = [W1 | b1 | 0...] K-padded 8->16      -> bf16 [2048][16]
//         (col 8 = b1[f]; ffn sets Q's k=8 input to 1.0 so the MFMA adds bias)
//   W2P = W2 in 32x32x16 MFMA B-fragment order:
//         [ntile(16)][kstep(128)][lane(64)][8]
//         element = W2[ntile*32 + (lane&31)][kstep*16 + (lane>>5)*8 + j]
// ---------------------------------------------------------------------------
__global__ __launch_bounds__(256) void prep_kernel(
    const float* __restrict__ x, const float* __restrict__ theta,
    const float* __restrict__ W1, const float* __restrict__ b1,
    const float* __restrict__ W2,
    short* __restrict__ W2P, short* __restrict__ Qz, short* __restrict__ W1z)
{
    int gid = blockIdx.x * 256 + threadIdx.x;
    if (gid < 131072) {                       // W2P
        int lane = gid & 63;
        int ks   = (gid >> 6) & 127;
        int nt   = gid >> 13;
        int n = nt * 32 + (lane & 31);
        int k = ks * 16 + (lane >> 5) * 8;
        const float4* p = (const float4*)(W2 + n * 2048 + k);
        float4 v0 = p[0], v1 = p[1];
        short8 o;
        o[0] = f2bf(v0.x); o[1] = f2bf(v0.y); o[2] = f2bf(v0.z); o[3] = f2bf(v0.w);
        o[4] = f2bf(v1.x); o[5] = f2bf(v1.y); o[6] = f2bf(v1.z); o[7] = f2bf(v1.w);
        *(short8*)(W2P + gid * 8) = o;
    } else if (gid < 131072 + 32768) {        // Qz
        int t = gid - 131072;
        const float4* xp = (const float4*)(x + t * 512);
        float4 x0 = xp[0], x1 = xp[1];
        float xv[8] = {x0.x, x0.y, x0.z, x0.w, x1.x, x1.y, x1.z, x1.w};
        short8 q;
#pragma unroll
        for (int c = 0; c < 8; ++c)
            q[c] = f2bf(cosf(xv[c]) * cosf(theta[c]));
        *(short8*)(Qz + t * 8) = q;
    } else if (gid < 131072 + 32768 + 2048) { // W1z rows: [W1(8) | b1 | 0x7]
        int f = gid - (131072 + 32768);
        const float4* wp = (const float4*)(W1 + f * 8);
        float4 w0 = wp[0], w1 = wp[1];
        short8 wv;
        wv[0] = f2bf(w0.x); wv[1] = f2bf(w0.y); wv[2] = f2bf(w0.z); wv[3] = f2bf(w0.w);
        wv[4] = f2bf(w1.x); wv[5] = f2bf(w1.y); wv[6] = f2bf(w1.z); wv[7] = f2bf(w1.w);
        short8 bz = {0,0,0,0,0,0,0,0};
        bz[0] = f2bf(b1[f]);                  // k=8 slot carries the bias
        *(short8*)(W1z + f * 16) = wv;
        *(short8*)(W1z + f * 16 + 8) = bz;
    }
}

// ---------------------------------------------------------------------------
// Stage 1: H^T tile (64 f x 128 m) for one K-tile. Bias comes in via the
// k=8 MFMA slot; epilogue is relu + truncation-pack (v_perm) + b64 LDS write.
// ---------------------------------------------------------------------------
__device__ __forceinline__ void stage1_tile(
    short8 a1, const short8* qf, short* __restrict__ dst,
    int wx, int wy, int lh, int l31)
{
#pragma unroll
    for (int i = 0; i < 2; ++i) {
        float16_t d1 = __builtin_amdgcn_mfma_f32_32x32x16_bf16(
            a1, qf[i], zero16(), 0, 0, 0);
        const int m = wy * 64 + i * 32 + l31;        // C/D col = m
#pragma unroll
        for (int g = 0; g < 4; ++g) {                // rows f = wx*32+4lh+8g+r
            float v0 = fmaxf(d1[g * 4 + 0], 0.0f);
            float v1 = fmaxf(d1[g * 4 + 1], 0.0f);
            float v2 = fmaxf(d1[g * 4 + 2], 0.0f);
            float v3 = fmaxf(d1[g * 4 + 3], 0.0f);
            uint2 pp;                                 // truncation bf16 pack
            pp.x = __builtin_amdgcn_perm(fbits(v1), fbits(v0), 0x07060302u);
            pp.y = __builtin_amdgcn_perm(fbits(v3), fbits(v2), 0x07060302u);
            *(uint2*)(dst + (wx * 4 + g) * 1024 + m * 8 + 4 * lh) = pp;
        }
    }
}

// ---------------------------------------------------------------------------
// Fused FFN: 1024 blocks of 128 tokens x 128 out-features -> 4 blocks/CU
// resident (VGPR<=128, LDS 32KB). BK=64, ping-pong Hs, one barrier per
// K-iter; inter-block TLP hides barrier drains and LDS/L2 latency.
// ---------------------------------------------------------------------------
__global__ __launch_bounds__(256, 4) void ffn_kernel(
    const short* __restrict__ Qz, const short* __restrict__ W1z,
    const short* __restrict__ W2P, const float* __restrict__ b2,
    float* __restrict__ out)
{
    __shared__ short Hs[2 * 8192];            // 2 x 16KB ping-pong, [c][m][8]

    const int tid  = threadIdx.x;
    const int lane = tid & 63;
    const int w    = tid >> 6;                 // wave 0..3
    const int wy = w & 1, wx = w >> 1;         // m-half (64) / f- or n-half
    const int l31 = lane & 31, lh = lane >> 5;
    const int bid = blockIdx.x;
    const int nt = bid & 3, mt = bid >> 2;     // 4 n-tiles x 256 m-tiles
    const int m0 = mt * 128, n0 = nt * 128;

    // stage-1 B operand: Q rows (k 0..7) for lh=0; k=8 -> 1.0 for bias row
    short8 qf[2];
#pragma unroll
    for (int i = 0; i < 2; ++i) {
        short8 v = {0,0,0,0,0,0,0,0};
        if (lh == 0)
            v = *(const short8*)(Qz + (m0 + wy * 64 + i * 32 + l31) * 8);
        else
            v[0] = (short)0x3F80;              // bf16(1.0)
        qf[i] = v;
    }

    // 32-bit W2P offsets (short units): ntile*65536 + kstep*512 + lane*8
    int w2base[2];
#pragma unroll
    for (int j = 0; j < 2; ++j)
        w2base[j] = (nt * 4 + wx * 2 + j) * 65536 + lane * 8;

    float16_t acc[2][2];
#pragma unroll
    for (int i = 0; i < 2; ++i)
#pragma unroll
        for (int j = 0; j < 2; ++j) acc[i][j] = zero16();

    // prologue: stage 1 for kt=0 into half 0
    {
        short8 a1 = *(const short8*)(W1z + (wx * 32 + l31) * 16 + lh * 8);
        stage1_tile(a1, qf, Hs, wx, wy, lh, l31);
    }
    __syncthreads();

    for (int kt = 0; kt < 32; ++kt) {
        const int p = kt & 1;

        // a1 for the stage-1 executed this iter (H for kt+1)
        short8 a1 = {0,0,0,0,0,0,0,0};
        if (kt < 31)
            a1 = *(const short8*)(W1z + ((kt + 1) * 64 + wx * 32 + l31) * 16 + lh * 8);

        // hoisted W2P B-fragments for THIS kt (L2 latency hidden by stage 1)
        short8 bfv[4][2];
#pragma unroll
        for (int ks = 0; ks < 4; ++ks)
#pragma unroll
            for (int j = 0; j < 2; ++j)
                bfv[ks][j] = *(const short8*)(W2P + w2base[j] + (kt * 4 + ks) * 512);

        // stage 1 for kt+1 into the other half
        if (kt < 31)
            stage1_tile(a1, qf, Hs + (p ^ 1) * 8192, wx, wy, lh, l31);

        // stage 2: 2x2 tiles of 32x32, 4 ksteps of 16
        const short* rd = Hs + p * 8192;
#pragma unroll
        for (int ks = 0; ks < 4; ++ks) {
            short8 af[2];
#pragma unroll
            for (int i = 0; i < 2; ++i)
                af[i] = *(const short8*)(rd + (ks * 2 + lh) * 1024 +
                                         (wy * 64 + i * 32 + l31) * 8);
#pragma unroll
            for (int i = 0; i < 2; ++i)
#pragma unroll
                for (int j = 0; j < 2; ++j)
                    acc[i][j] = __builtin_amdgcn_mfma_f32_32x32x16_bf16(
                        af[i], bfv[ks][j], acc[i][j], 0, 0, 0);
        }
        __syncthreads();
    }

    // ---- epilogue: out(fp32) = acc + b2 ----
#pragma unroll
    for (int j = 0; j < 2; ++j) {
        const int n = n0 + wx * 64 + j * 32 + l31;
        const float b2v = b2[n];
#pragma unroll
        for (int i = 0; i < 2; ++i) {
            const int base = (m0 + wy * 64 + i * 32 + 4 * lh) * 512 + n;
#pragma unroll
            for (int r = 0; r < 16; ++r) {
                const int off = ((r & 3) + 8 * (r >> 2)) * 512;
                out[base + off] = acc[i][j][r] + b2v;
            }
        }
    }
}

// ---------------------------------------------------------------------------
extern "C" void kernel_launch(void* const* d_in, const int* in_sizes, int n_in,
                              void* d_out, int out_size, void* d_ws, size_t ws_size,
                              hipStream_t stream)
{
    const float* x     = (const float*)d_in[0];  // [8,4096,512] fp32
    const float* theta = (const float*)d_in[1];  // [8] fp32
    const float* W1    = (const float*)d_in[2];  // [2048,8] fp32
    const float* b1    = (const float*)d_in[3];  // [2048] fp32
    const float* W2    = (const float*)d_in[4];  // [512,2048] fp32
    const float* b2    = (const float*)d_in[5];  // [512] fp32
    float* out = (float*)d_out;                  // [8,4096,512] fp32

    short* W2P = (short*)d_ws;                          // 2 MB
    short* Qz  = (short*)((char*)d_ws + 2097152);       // 512 KB
    short* W1z = (short*)((char*)d_ws + 2621440);       // 64 KB

    prep_kernel<<<648, 256, 0, stream>>>(x, theta, W1, b1, W2, W2P, Qz, W1z);
    ffn_kernel<<<1024, 256, 0, stream>>>(Qz, W1z, W2P, b2, out);
}

// Round 6
// 172.018 us; speedup vs baseline: 1.0594x; 1.0594x over previous
//
#include <hip/hip_runtime.h>
#include <math.h>

typedef __attribute__((ext_vector_type(8)))  short short8;
typedef __attribute__((ext_vector_type(16))) float float16_t;

__device__ __forceinline__ short f2bf(float f) {          // RNE (prep only)
    union { float f; unsigned u; } c; c.f = f;
    unsigned u = c.u + 0x7fffu + ((c.u >> 16) & 1u);
    return (short)(u >> 16);
}
__device__ __forceinline__ unsigned fbits(float f) {
    union { float f; unsigned u; } c; c.f = f; return c.u;
}
__device__ __forceinline__ float16_t zero16() {
    float16_t z;
#pragma unroll
    for (int r = 0; r < 16; ++r) z[r] = 0.0f;
    return z;
}

// ---------------------------------------------------------------------------
// Prep (fp32 in -> bf16 out):
//   Qz  = cos(x[...,:8])*cos(theta)            -> bf16 [32768][8]
//   W1z = [W1 | b1 | 0...] K-padded 8->16      -> bf16 [2048][16]
//         (col 8 = b1[f]; ffn sets Q's k=8 input to 1.0 so the MFMA adds bias)
//   W2P = W2 in 32x32x16 MFMA B-fragment order:
//         [ntile(16)][kstep(128)][lane(64)][8]
//         element = W2[ntile*32 + (lane&31)][kstep*16 + (lane>>5)*8 + j]
// ---------------------------------------------------------------------------
__global__ __launch_bounds__(256) void prep_kernel(
    const float* __restrict__ x, const float* __restrict__ theta,
    const float* __restrict__ W1, const float* __restrict__ b1,
    const float* __restrict__ W2,
    short* __restrict__ W2P, short* __restrict__ Qz, short* __restrict__ W1z)
{
    int gid = blockIdx.x * 256 + threadIdx.x;
    if (gid < 131072) {                       // W2P
        int lane = gid & 63;
        int ks   = (gid >> 6) & 127;
        int nt   = gid >> 13;
        int n = nt * 32 + (lane & 31);
        int k = ks * 16 + (lane >> 5) * 8;
        const float4* p = (const float4*)(W2 + n * 2048 + k);
        float4 v0 = p[0], v1 = p[1];
        short8 o;
        o[0] = f2bf(v0.x); o[1] = f2bf(v0.y); o[2] = f2bf(v0.z); o[3] = f2bf(v0.w);
        o[4] = f2bf(v1.x); o[5] = f2bf(v1.y); o[6] = f2bf(v1.z); o[7] = f2bf(v1.w);
        *(short8*)(W2P + gid * 8) = o;
    } else if (gid < 131072 + 32768) {        // Qz
        int t = gid - 131072;
        const float4* xp = (const float4*)(x + t * 512);
        float4 x0 = xp[0], x1 = xp[1];
        float xv[8] = {x0.x, x0.y, x0.z, x0.w, x1.x, x1.y, x1.z, x1.w};
        short8 q;
#pragma unroll
        for (int c = 0; c < 8; ++c)
            q[c] = f2bf(cosf(xv[c]) * cosf(theta[c]));
        *(short8*)(Qz + t * 8) = q;
    } else if (gid < 131072 + 32768 + 2048) { // W1z rows: [W1(8) | b1 | 0x7]
        int f = gid - (131072 + 32768);
        const float4* wp = (const float4*)(W1 + f * 8);
        float4 w0 = wp[0], w1 = wp[1];
        short8 wv;
        wv[0] = f2bf(w0.x); wv[1] = f2bf(w0.y); wv[2] = f2bf(w0.z); wv[3] = f2bf(w0.w);
        wv[4] = f2bf(w1.x); wv[5] = f2bf(w1.y); wv[6] = f2bf(w1.z); wv[7] = f2bf(w1.w);
        short8 bz = {0,0,0,0,0,0,0,0};
        bz[0] = f2bf(b1[f]);                  // k=8 slot carries the bias
        *(short8*)(W1z + f * 16) = wv;
        *(short8*)(W1z + f * 16 + 8) = bz;
    }
}

// ---------------------------------------------------------------------------
// Stage 1: H^T tile (64 f x 128 m) for one K-tile. Bias comes in via the
// k=8 MFMA slot; epilogue is relu + truncation-pack (v_perm) + b64 LDS write.
// ---------------------------------------------------------------------------
__device__ __forceinline__ void stage1_tile(
    short8 a1, const short8* qf, short* __restrict__ dst,
    int wx, int wy, int lh, int l31)
{
#pragma unroll
    for (int i = 0; i < 2; ++i) {
        float16_t d1 = __builtin_amdgcn_mfma_f32_32x32x16_bf16(
            a1, qf[i], zero16(), 0, 0, 0);
        const int m = wy * 64 + i * 32 + l31;        // C/D col = m
#pragma unroll
        for (int g = 0; g < 4; ++g) {                // rows f = wx*32+4lh+8g+r
            float v0 = fmaxf(d1[g * 4 + 0], 0.0f);
            float v1 = fmaxf(d1[g * 4 + 1], 0.0f);
            float v2 = fmaxf(d1[g * 4 + 2], 0.0f);
            float v3 = fmaxf(d1[g * 4 + 3], 0.0f);
            uint2 pp;                                 // truncation bf16 pack
            pp.x = __builtin_amdgcn_perm(fbits(v1), fbits(v0), 0x07060302u);
            pp.y = __builtin_amdgcn_perm(fbits(v3), fbits(v2), 0x07060302u);
            *(uint2*)(dst + (wx * 4 + g) * 1024 + m * 8 + 4 * lh) = pp;
        }
    }
}

// ---------------------------------------------------------------------------
// Fused FFN: 512 blocks (2/CU), 128 tokens x 256 out-features, BK=64,
// ping-pong Hs, one barrier per K-iter. Software-pipelined global loads:
//   a1 (W1 rows) carried one iteration ahead;
//   B-fragments ks{0,1} prefetched across the barrier (registers),
//   B-fragments ks{2,3} issued at iter top, consumed after 16 MFMAs.
// Uniform base pointers advance per iter (SGPR adds); lane offsets are
// loop-invariant VGPRs + immediate offsets -> ~zero per-iter address VALU.
// ---------------------------------------------------------------------------
__global__ __launch_bounds__(256, 2) void ffn_kernel(
    const short* __restrict__ Qz, const short* __restrict__ W1z,
    const short* __restrict__ W2P, const float* __restrict__ b2,
    float* __restrict__ out)
{
    __shared__ short Hs[2 * 8192];            // 2 x 16KB ping-pong, [c][m][8]

    const int tid  = threadIdx.x;
    const int lane = tid & 63;
    const int w    = tid >> 6;                 // wave 0..3
    const int wy = w & 1, wx = w >> 1;         // m-half (64), n-half (128)
    const int l31 = lane & 31, lh = lane >> 5;
    const int bid = blockIdx.x;
    const int nt = bid & 1, mt = bid >> 1;
    const int m0 = mt * 128, n0 = nt * 256;

    // stage-1 B operand: Q rows (k 0..7) for lh=0; k=8 -> 1.0 for bias row
    short8 qf[2];
#pragma unroll
    for (int i = 0; i < 2; ++i) {
        short8 v = {0,0,0,0,0,0,0,0};
        if (lh == 0)
            v = *(const short8*)(Qz + (m0 + wy * 64 + i * 32 + l31) * 8);
        else
            v[0] = (short)0x3F80;              // bf16(1.0)
        qf[i] = v;
    }

    // loop-invariant lane offsets (short units)
    int w2off[4];
#pragma unroll
    for (int j = 0; j < 4; ++j)
        w2off[j] = (nt * 8 + wx * 4 + j) * 65536 + lane * 8;
    const int a1off = (wx * 32 + l31) * 16 + lh * 8;

    float16_t acc[2][4];
#pragma unroll
    for (int i = 0; i < 2; ++i)
#pragma unroll
        for (int j = 0; j < 4; ++j) acc[i][j] = zero16();

    // ---- prologue ----
    const short* W2Pk = W2P;                   // advanced 2048/iter (= 1 kt)
    const short* W1za = W1z + 2048;            // rows for kt+2, 1024/iter

    short8 bfvA[2][4], bfvB[2][4];
#pragma unroll
    for (int ks = 0; ks < 2; ++ks)
#pragma unroll
        for (int j = 0; j < 4; ++j)
            bfvA[ks][j] = *(const short8*)(W2Pk + w2off[j] + ks * 512);
    short8 a1n = *(const short8*)(W1z + 1024 + a1off);   // W1 rows for kt=1
    {
        short8 a1_0 = *(const short8*)(W1z + a1off);
        stage1_tile(a1_0, qf, Hs, wx, wy, lh, l31);      // H(0) -> half 0
    }
    __syncthreads();

    for (int kt = 0; kt < 32; ++kt) {
        const int p = kt & 1;
        short* wr = Hs + (p ^ 1) * 8192;
        const short* rd = Hs + p * 8192;

        // issue B(kt, ks 2..3) now; consumed after 16 MFMAs of shadow
#pragma unroll
        for (int ks = 0; ks < 2; ++ks)
#pragma unroll
            for (int j = 0; j < 4; ++j)
                bfvB[ks][j] = *(const short8*)(W2Pk + w2off[j] + (ks + 2) * 512);

        // stage 1 for kt+1 (a1 already in registers -> starts immediately)
        if (kt < 31)
            stage1_tile(a1n, qf, wr, wx, wy, lh, l31);
        if (kt < 30)
            a1n = *(const short8*)(W1za + a1off);        // W1 rows for kt+2
        W1za += 1024;

        // stage 2, phase A: ks 0..1 with prefetched bfvA
#pragma unroll
        for (int ks = 0; ks < 2; ++ks) {
            short8 af[2];
#pragma unroll
            for (int i = 0; i < 2; ++i)
                af[i] = *(const short8*)(rd + (ks * 2 + lh) * 1024 +
                                         (wy * 64 + i * 32 + l31) * 8);
#pragma unroll
            for (int i = 0; i < 2; ++i)
#pragma unroll
                for (int j = 0; j < 4; ++j)
                    acc[i][j] = __builtin_amdgcn_mfma_f32_32x32x16_bf16(
                        af[i], bfvA[ks][j], acc[i][j], 0, 0, 0);
        }

        // prefetch B(kt+1, ks 0..1) across the barrier (bfvA regs now free)
        W2Pk += 2048;
        if (kt < 31) {
#pragma unroll
            for (int ks = 0; ks < 2; ++ks)
#pragma unroll
                for (int j = 0; j < 4; ++j)
                    bfvA[ks][j] = *(const short8*)(W2Pk + w2off[j] + ks * 512);
        }

        // stage 2, phase B: ks 2..3 with bfvB
#pragma unroll
        for (int ks = 0; ks < 2; ++ks) {
            short8 af[2];
#pragma unroll
            for (int i = 0; i < 2; ++i)
                af[i] = *(const short8*)(rd + ((ks + 2) * 2 + lh) * 1024 +
                                         (wy * 64 + i * 32 + l31) * 8);
#pragma unroll
            for (int i = 0; i < 2; ++i)
#pragma unroll
                for (int j = 0; j < 4; ++j)
                    acc[i][j] = __builtin_amdgcn_mfma_f32_32x32x16_bf16(
                        af[i], bfvB[ks][j], acc[i][j], 0, 0, 0);
        }

        __syncthreads();
    }

    // ---- epilogue: out(fp32) = acc + b2 ----
#pragma unroll
    for (int j = 0; j < 4; ++j) {
        const int n = n0 + wx * 128 + j * 32 + l31;
        const float b2v = b2[n];
#pragma unroll
        for (int i = 0; i < 2; ++i) {
            const int base = (m0 + wy * 64 + i * 32 + 4 * lh) * 512 + n;
#pragma unroll
            for (int r = 0; r < 16; ++r) {
                const int off = ((r & 3) + 8 * (r >> 2)) * 512;
                out[base + off] = acc[i][j][r] + b2v;
            }
        }
    }
}

// ---------------------------------------------------------------------------
extern "C" void kernel_launch(void* const* d_in, const int* in_sizes, int n_in,
                              void* d_out, int out_size, void* d_ws, size_t ws_size,
                              hipStream_t stream)
{
    const float* x     = (const float*)d_in[0];  // [8,4096,512] fp32
    const float* theta = (const float*)d_in[1];  // [8] fp32
    const float* W1    = (const float*)d_in[2];  // [2048,8] fp32
    const float* b1    = (const float*)d_in[3];  // [2048] fp32
    const float* W2    = (const float*)d_in[4];  // [512,2048] fp32
    const float* b2    = (const float*)d_in[5];  // [512] fp32
    float* out = (float*)d_out;                  // [8,4096,512] fp32

    short* W2P = (short*)d_ws;                          // 2 MB
    short* Qz  = (short*)((char*)d_ws + 2097152);       // 512 KB
    short* W1z = (short*)((char*)d_ws + 2621440);       // 64 KB

    prep_kernel<<<648, 256, 0, stream>>>(x, theta, W1, b1, W2, W2P, Qz, W1z);
    ffn_kernel<<<512, 256, 0, stream>>>(Qz, W1z, W2P, b2, out);
}